// Round 7
// baseline (287.849 us; speedup 1.0000x reference)
//
#include <hip/hip_runtime.h>

#define NN 12800
#define NE 204800
#define BCAP 64   // bucket capacity per node; P(deg>64) ~ 1e-18
#define NPB 50    // (k_setup grid math only)
#define BTHR 512  // k_round: 8 waves/block, 1 wave per node
#define WPB 8     // waves (nodes) per block
#define NBLK2 (NN / WPB)  // 1600 blocks; 4 resident/CU -> 32 waves/CU (100%)

// packed-weight layout (floats) -- shared by g_wpack and s_pack
#define OFF_W2 0        // [j*276 + kp*16 + d], bias at [j*276+256+kp]  (4416)
#define OFF_CR 4416     // [k*20+d] = cr[d*16+k]                        (320)
#define OFF_WI 4736     // [row*20+d]                                   (960)
#define OFF_WH 5696     // [row*20+d]                                   (960)
#define OFF_CB 6656     // (16)
#define OFF_BI 6672     // (48)
#define OFF_BH 6720     // (48)
#define PACKN  6768     // total floats (27072 B)

// ---------------- static device scratch (~57 MB) ----------------
__device__ __align__(16) float g_outA[NN * 16];        // node features ping
__device__ __align__(16) float g_outB[NN * 16];        // node features pong
__device__ __align__(16) float g_ehsB[NN * BCAP * 16]; // eh buckets, dst-grouped
__device__ __align__(16) int g_srcB[NN * BCAP];        // src per bucket slot
__device__ int g_cnt[NN];                              // in-degree / cursor (reset by last round)
__device__ int g_perm[NN];                             // degree-balanced node assignment
__device__ __align__(16) float g_wpack[PACKN];         // pre-transposed weights

// ---- S0: lin0 + eh/bucket scatter (edge-parallel); block 0 builds wpack ----
__global__ __launch_bounds__(256) void k_setup(const int* __restrict__ ei,
                                               const float* __restrict__ x,
                                               const float* __restrict__ lw,
                                               const float* __restrict__ lb,
                                               const float* __restrict__ attr,
                                               const float* __restrict__ w1,
                                               const float* __restrict__ b1,
                                               const float* __restrict__ nn2_w,
                                               const float* __restrict__ nn2_b,
                                               const float* __restrict__ cr,
                                               const float* __restrict__ cb,
                                               const float* __restrict__ wi,
                                               const float* __restrict__ wh,
                                               const float* __restrict__ bi,
                                               const float* __restrict__ bh) {
    int gid = blockIdx.x * 256 + threadIdx.x;

    if (blockIdx.x == 0) {
        int tt = threadIdx.x;
        for (int i = tt; i < 4096; i += 256)
            g_wpack[OFF_W2 + (i & 15) * 276 + ((i >> 4) & 15) * 16 + (i >> 8)] = nn2_w[i];
        g_wpack[OFF_W2 + (tt >> 4) * 276 + 256 + (tt & 15)] = nn2_b[tt];
        g_wpack[OFF_CR + (tt & 15) * 20 + (tt >> 4)] = cr[tt];
        for (int i = tt; i < 768; i += 256) {
            g_wpack[OFF_WI + (i >> 4) * 20 + (i & 15)] = wi[i];
            g_wpack[OFF_WH + (i >> 4) * 20 + (i & 15)] = wh[i];
        }
        if (tt < 16) g_wpack[OFF_CB + tt] = cb[tt];
        if (tt < 48) { g_wpack[OFF_BI + tt] = bi[tt]; g_wpack[OFF_BH + tt] = bh[tt]; }
    }

    if (gid < NN) {
        int n = gid;
        float x0 = x[n * 3 + 0], x1 = x[n * 3 + 1], x2 = x[n * 3 + 2];
        float v[16];
#pragma unroll
        for (int j = 0; j < 16; ++j) {
            float t = lb[j] + x0 * lw[j * 3 + 0] + x1 * lw[j * 3 + 1] + x2 * lw[j * 3 + 2];
            v[j] = fmaxf(t, 0.0f);
        }
#pragma unroll
        for (int j = 0; j < 16; j += 4)
            *(float4*)(g_outA + n * 16 + j) = make_float4(v[j], v[j + 1], v[j + 2], v[j + 3]);
    }

    int e = gid;
    int s = ei[e], d = ei[NE + e];
    float4 a = *(const float4*)(attr + e * 4);
    float v[16];
#pragma unroll
    for (int j = 0; j < 16; ++j) {
        float t = b1[j] + a.x * w1[j * 4 + 0] + a.y * w1[j * 4 + 1] +
                  a.z * w1[j * 4 + 2] + a.w * w1[j * 4 + 3];
        v[j] = fmaxf(t, 0.0f);
    }
    int pos = atomicAdd(&g_cnt[d], 1);
    if (pos < BCAP) {
        int slot = d * BCAP + pos;
        g_srcB[slot] = s;
#pragma unroll
        for (int j = 0; j < 16; j += 4)
            *(float4*)(g_ehsB + slot * 16 + j) = make_float4(v[j], v[j + 1], v[j + 2], v[j + 3]);
    }
}

// ---- S1: degree-balanced permutation (counting sort by degree, 1 block) ----
// sorted rank s -> block s%1600, wave s/1600 (strided: per-block degree
// totals equalize; one NODE per WAVE -> no intra-wave degree divergence).
__global__ __launch_bounds__(1024) void k_perm() {
    __shared__ int hist[64];
    int t = threadIdx.x;
    if (t < 64) hist[t] = 0;
    __syncthreads();
    for (int n = t; n < NN; n += 1024)
        atomicAdd(&hist[min(g_cnt[n], 63)], 1);
    __syncthreads();
    if (t < 64) {
        int v = hist[t];
        int incl = v;
#pragma unroll
        for (int off = 1; off < 64; off <<= 1) {
            int u = __shfl_up(incl, off, 64);
            if (t >= off) incl += u;
        }
        hist[t] = incl - v;                      // exclusive base -> cursor
    }
    __syncthreads();
    for (int n = t; n < NN; n += 1024) {
        int s = atomicAdd(&hist[min(g_cnt[n], 63)], 1);
        int blk = s % NBLK2;
        int wv  = s / NBLK2;                     // 0..7
        g_perm[blk * WPB + wv] = n;
    }
}

// ---- one round. v7: ONE WAVE (64 lanes) PER NODE. ----
// 4 subgroups of 16 lanes; subgroup sg handles edges q == sg (mod 4):
//   serial edge chain 16 -> 4 iters; eh read = 256B fully coalesced/wave.
// Gd cross-summed via shfl_xor(16/32); contraction kp-split 4-way
// (kp = 4m+sg, 2-way-bank-friendly); butterfly 2 array + 2 scalar levels.
// 512thr x 1600 blocks -> 4 blocks/CU = 32 waves/CU (100% occupancy,
// was 12.5 waves; attacks the latency-bound round directly).
__global__ __launch_bounds__(BTHR) void k_round(float* __restrict__ out_final,
                                                int flip, int last) {
    __shared__ __align__(16) float s_pack[PACKN];
    int t = threadIdx.x;
    {   // straight coalesced float4 copy of the pre-transposed pack
        const float4* srcp = (const float4*)g_wpack;
        float4* dstp = (float4*)s_pack;
        for (int idx = t; idx < PACKN / 4; idx += BTHR) dstp[idx] = srcp[idx];
    }
    __syncthreads();

    const float* s_W2  = s_pack + OFF_W2;
    const float* s_crT = s_pack + OFF_CR;
    const float* s_wi  = s_pack + OFF_WI;
    const float* s_wh  = s_pack + OFF_WH;
    const float* s_cb  = s_pack + OFF_CB;
    const float* s_bi  = s_pack + OFF_BI;
    const float* s_bh  = s_pack + OFF_BH;

    const float* cur = flip ? g_outB : g_outA;
    float*       nxt = flip ? g_outA : g_outB;

    const int wave = t >> 6, lane = t & 63;
    const int sg = lane >> 4, j = lane & 15;
    const int n = min(max(g_perm[blockIdx.x * WPB + wave], 0), NN - 1);
    int deg = min(g_cnt[n], BCAP);               // wave-uniform
    if (last && lane == 0) g_cnt[n] = 0;         // reset for next call's k_setup
    const int base = n * BCAP;

    // ---- src prefetch: lane holds slot `lane` (256B fully coalesced) ----
    int sB = min(max(g_srcB[base + lane], 0), NN - 1);

    // ---- G-row accumulation: subgroup sg takes edges q = 4i+sg ----
    float Gd[16];
#pragma unroll
    for (int d = 0; d < 16; ++d) Gd[d] = 0.0f;
    float r16 = 0.0f;

    for (int i = 0; i < 16; ++i) {
        if (4 * i >= deg) break;                 // wave-uniform break
        int q = 4 * i + sg;
        int s = __shfl(sB, q, 64);               // register broadcast
        if (q < deg) {                           // tail-iter lane mask only
            const float* orow = cur + s * 16;
            float ej = g_ehsB[(base + q) * 16 + j];  // 256B coalesced per wave
            float4 o0 = *(const float4*)(orow + 0);  // broadcast per subgroup
            float4 o1 = *(const float4*)(orow + 4);
            float4 o2 = *(const float4*)(orow + 8);
            float4 o3 = *(const float4*)(orow + 12);
            Gd[0]  += ej * o0.x; Gd[1]  += ej * o0.y; Gd[2]  += ej * o0.z; Gd[3]  += ej * o0.w;
            Gd[4]  += ej * o1.x; Gd[5]  += ej * o1.y; Gd[6]  += ej * o1.z; Gd[7]  += ej * o1.w;
            Gd[8]  += ej * o2.x; Gd[9]  += ej * o2.y; Gd[10] += ej * o2.z; Gd[11] += ej * o2.w;
            Gd[12] += ej * o3.x; Gd[13] += ej * o3.y; Gd[14] += ej * o3.z; Gd[15] += ej * o3.w;
            r16 += orow[j];
        }
    }

    // ---- cross-subgroup reduce: full-edge sums at every lane ----
#pragma unroll
    for (int d = 0; d < 16; ++d) {
        Gd[d] += __shfl_xor(Gd[d], 16);
        Gd[d] += __shfl_xor(Gd[d], 32);
    }
    r16 += __shfl_xor(r16, 16);
    r16 += __shfl_xor(r16, 32);

    // ---- contraction: part[m] for kp = 4m + sg (4 kp per lane) ----
    const float* wj = s_W2 + j * 276;
    float part[4];
#pragma unroll
    for (int m = 0; m < 4; ++m) {
        const float* w = wj + (4 * m + sg) * 16;
        float4 w0 = *(const float4*)(w + 0);
        float4 w1 = *(const float4*)(w + 4);
        float4 w2 = *(const float4*)(w + 8);
        float4 w3 = *(const float4*)(w + 12);
        part[m] = Gd[0] * w0.x + Gd[1] * w0.y + Gd[2] * w0.z + Gd[3] * w0.w
                + Gd[4] * w1.x + Gd[5] * w1.y + Gd[6] * w1.z + Gd[7] * w1.w
                + Gd[8] * w2.x + Gd[9] * w2.y + Gd[10] * w2.z + Gd[11] * w2.w
                + Gd[12] * w3.x + Gd[13] * w3.y + Gd[14] * w3.z + Gd[15] * w3.w;
        part[m] += r16 * wj[256 + 4 * m + sg];   // fold bias row
    }

    // ---- j-reduction over 16 lanes: 2 array levels + 2 scalar levels ----
    // rule #20: static indices; runtime keep/other via VALUE selects.
    const bool sel0 = (j & 1) != 0;
    const bool sel1 = ((j >> 1) & 1) != 0;
    float w2v[2];
#pragma unroll
    for (int i = 0; i < 2; ++i) {
        float a = part[2 * i], b = part[2 * i + 1];
        float keepv = sel0 ? b : a;
        float othv  = sel0 ? a : b;
        w2v[i] = keepv + __shfl_xor(othv, 1);
    }
    float vsum;
    {
        float a = w2v[0], b = w2v[1];
        float keepv = sel1 ? b : a;
        float othv  = sel1 ? a : b;
        vsum = keepv + __shfl_xor(othv, 2);
    }
    vsum += __shfl_xor(vsum, 4);
    vsum += __shfl_xor(vsum, 8);
    // lane (16sg + j) now holds aggr_raw[kp = 4*(j&3) + sg]

    // ---- redistribute: lane needs k = lane&15 -> src lane 16*(k&3)+(k>>2) ----
    const int kk = lane & 15;
    float aggr = __shfl(vsum, ((kk & 3) << 4) | (kk >> 2), 64);
    float invd = 1.0f / (float)(deg > 0 ? deg : 1);
    float a_k = aggr * invd;

    // ---- node update: conv + GRU (replicated per subgroup; store lane<16) ----
    const float* nrow = cur + n * 16;
    float4 q0v = *(const float4*)(nrow + 0);
    float4 q1v = *(const float4*)(nrow + 4);
    float4 q2v = *(const float4*)(nrow + 8);
    float4 q3v = *(const float4*)(nrow + 12);
    float o[16] = {q0v.x, q0v.y, q0v.z, q0v.w, q1v.x, q1v.y, q1v.z, q1v.w,
                   q2v.x, q2v.y, q2v.z, q2v.w, q3v.x, q3v.y, q3v.z, q3v.w};
    float ok = nrow[kk];                         // own element: direct load

    float mcc = s_cb[kk] + a_k;
    {
        const float* c = s_crT + kk * 20;
        float4 c0 = *(const float4*)(c + 0);
        float4 c1 = *(const float4*)(c + 4);
        float4 c2 = *(const float4*)(c + 8);
        float4 c3 = *(const float4*)(c + 12);
        mcc += o[0] * c0.x + o[1] * c0.y + o[2] * c0.z + o[3] * c0.w
             + o[4] * c1.x + o[5] * c1.y + o[6] * c1.z + o[7] * c1.w
             + o[8] * c2.x + o[9] * c2.y + o[10] * c2.z + o[11] * c2.w
             + o[12] * c3.x + o[13] * c3.y + o[14] * c3.z + o[15] * c3.w;
    }
    float m = fmaxf(mcc, 0.0f);

    float md[16];
#pragma unroll
    for (int d = 0; d < 16; ++d) md[d] = __shfl(m, d, 16);  // subgroup-local

    float ir = s_bi[kk], iz = s_bi[16 + kk], in_ = s_bi[32 + kk];
    float hr = s_bh[kk], hz = s_bh[16 + kk], hh = s_bh[32 + kk];
#pragma unroll
    for (int g = 0; g < 3; ++g) {
        const float* wrow_i = s_wi + (g * 16 + kk) * 20;
        const float* wrow_h = s_wh + (g * 16 + kk) * 20;
        float acc_i = 0.0f, acc_h = 0.0f;
#pragma unroll
        for (int d4 = 0; d4 < 4; ++d4) {
            float4 wiv = *(const float4*)(wrow_i + d4 * 4);
            float4 whv = *(const float4*)(wrow_h + d4 * 4);
            acc_i += md[d4 * 4] * wiv.x + md[d4 * 4 + 1] * wiv.y
                   + md[d4 * 4 + 2] * wiv.z + md[d4 * 4 + 3] * wiv.w;
            acc_h += o[d4 * 4] * whv.x + o[d4 * 4 + 1] * whv.y
                   + o[d4 * 4 + 2] * whv.z + o[d4 * 4 + 3] * whv.w;
        }
        if (g == 0) { ir += acc_i; hr += acc_h; }
        else if (g == 1) { iz += acc_i; hz += acc_h; }
        else { in_ += acc_i; hh += acc_h; }
    }
    float rg = 1.0f / (1.0f + __expf(-(ir + hr)));
    float z  = 1.0f / (1.0f + __expf(-(iz + hz)));
    float nh = tanhf(in_ + rg * hh);
    float hnew = (1.0f - z) * nh + z * ok;

    if (lane < 16) {
        if (last) out_final[n * 16 + kk] = hnew;
        else      nxt[n * 16 + kk] = hnew;
    }
}

extern "C" void kernel_launch(void* const* d_in, const int* in_sizes, int n_in,
                              void* d_out, int out_size, void* d_ws, size_t ws_size,
                              hipStream_t stream) {
    const float* x         = (const float*)d_in[0];
    const int*   ei        = (const int*)d_in[1];
    const float* edge_attr = (const float*)d_in[2];
    const float* lin0_w    = (const float*)d_in[3];
    const float* lin0_b    = (const float*)d_in[4];
    const float* nn1_w     = (const float*)d_in[5];
    const float* nn1_b     = (const float*)d_in[6];
    const float* nn2_w     = (const float*)d_in[7];
    const float* nn2_b     = (const float*)d_in[8];
    const float* conv_root = (const float*)d_in[9];
    const float* conv_bias = (const float*)d_in[10];
    const float* gru_w_ih  = (const float*)d_in[11];
    const float* gru_w_hh  = (const float*)d_in[12];
    const float* gru_b_ih  = (const float*)d_in[13];
    const float* gru_b_hh  = (const float*)d_in[14];
    float* out = (float*)d_out;

    k_setup<<<NE / 256, 256, 0, stream>>>(ei, x, lin0_w, lin0_b, edge_attr,
                                          nn1_w, nn1_b, nn2_w, nn2_b, conv_root,
                                          conv_bias, gru_w_ih, gru_w_hh,
                                          gru_b_ih, gru_b_hh);
    k_perm<<<1, 1024, 0, stream>>>();

    for (int r = 0; r < 6; ++r) {
        k_round<<<NBLK2, BTHR, 0, stream>>>(out, r & 1, r == 5 ? 1 : 0);
    }
}

// Round 8
// 213.196 us; speedup vs baseline: 1.3502x; 1.3502x over previous
//
#include <hip/hip_runtime.h>

#define NN 12800
#define NE 204800
#define BCAP 64   // bucket capacity per node; P(deg>64) ~ 1e-18
#define NPB 50    // nodes per round-block; 256 blocks x 50 = 12800 = NN
#define RTHR (NPB * 16)  // 800 threads per round-block -> 1 block per CU

// packed-weight layout (floats) -- shared by g_wpack and s_pack
#define OFF_W2 0        // [j*276 + kp*16 + d], bias at [j*276+256+kp]  (4416)
#define OFF_CR 4416     // [k*20+d] = cr[d*16+k]                        (320)
#define OFF_WI 4736     // [row*20+d]                                   (960)
#define OFF_WH 5696     // [row*20+d]                                   (960)
#define OFF_CB 6656     // (16)
#define OFF_BI 6672     // (48)
#define OFF_BH 6720     // (48)
#define PACKN  6768     // total floats (27072 B)

// ---------------- static device scratch (~57 MB) ----------------
__device__ __align__(16) float g_outA[NN * 16];        // node features ping
__device__ __align__(16) float g_outB[NN * 16];        // node features pong
__device__ __align__(16) float g_ehsB[NN * BCAP * 16]; // eh buckets, dst-grouped
__device__ __align__(16) int g_srcB[NN * BCAP];        // src per bucket slot
__device__ int g_cnt[NN];                              // in-degree / cursor (reset by last round)
__device__ int g_perm[NN];                             // degree-balanced node assignment
__device__ __align__(16) float g_wpack[PACKN];         // pre-transposed weights

// ---- S0: lin0 + eh/bucket scatter (edge-parallel); block 0 builds wpack ----
__global__ __launch_bounds__(256) void k_setup(const int* __restrict__ ei,
                                               const float* __restrict__ x,
                                               const float* __restrict__ lw,
                                               const float* __restrict__ lb,
                                               const float* __restrict__ attr,
                                               const float* __restrict__ w1,
                                               const float* __restrict__ b1,
                                               const float* __restrict__ nn2_w,
                                               const float* __restrict__ nn2_b,
                                               const float* __restrict__ cr,
                                               const float* __restrict__ cb,
                                               const float* __restrict__ wi,
                                               const float* __restrict__ wh,
                                               const float* __restrict__ bi,
                                               const float* __restrict__ bh) {
    int gid = blockIdx.x * 256 + threadIdx.x;

    if (blockIdx.x == 0) {
        int tt = threadIdx.x;
        for (int i = tt; i < 4096; i += 256)
            g_wpack[OFF_W2 + (i & 15) * 276 + ((i >> 4) & 15) * 16 + (i >> 8)] = nn2_w[i];
        g_wpack[OFF_W2 + (tt >> 4) * 276 + 256 + (tt & 15)] = nn2_b[tt];
        g_wpack[OFF_CR + (tt & 15) * 20 + (tt >> 4)] = cr[tt];
        for (int i = tt; i < 768; i += 256) {
            g_wpack[OFF_WI + (i >> 4) * 20 + (i & 15)] = wi[i];
            g_wpack[OFF_WH + (i >> 4) * 20 + (i & 15)] = wh[i];
        }
        if (tt < 16) g_wpack[OFF_CB + tt] = cb[tt];
        if (tt < 48) { g_wpack[OFF_BI + tt] = bi[tt]; g_wpack[OFF_BH + tt] = bh[tt]; }
    }

    if (gid < NN) {
        int n = gid;
        float x0 = x[n * 3 + 0], x1 = x[n * 3 + 1], x2 = x[n * 3 + 2];
        float v[16];
#pragma unroll
        for (int j = 0; j < 16; ++j) {
            float t = lb[j] + x0 * lw[j * 3 + 0] + x1 * lw[j * 3 + 1] + x2 * lw[j * 3 + 2];
            v[j] = fmaxf(t, 0.0f);
        }
#pragma unroll
        for (int j = 0; j < 16; j += 4)
            *(float4*)(g_outA + n * 16 + j) = make_float4(v[j], v[j + 1], v[j + 2], v[j + 3]);
    }

    int e = gid;
    int s = ei[e], d = ei[NE + e];
    float4 a = *(const float4*)(attr + e * 4);
    float v[16];
#pragma unroll
    for (int j = 0; j < 16; ++j) {
        float t = b1[j] + a.x * w1[j * 4 + 0] + a.y * w1[j * 4 + 1] +
                  a.z * w1[j * 4 + 2] + a.w * w1[j * 4 + 3];
        v[j] = fmaxf(t, 0.0f);
    }
    int pos = atomicAdd(&g_cnt[d], 1);
    if (pos < BCAP) {
        int slot = d * BCAP + pos;
        g_srcB[slot] = s;
#pragma unroll
        for (int j = 0; j < 16; j += 4)
            *(float4*)(g_ehsB + slot * 16 + j) = make_float4(v[j], v[j + 1], v[j + 2], v[j + 3]);
    }
}

// ---- S1: degree-balanced permutation (counting sort by degree, 1 block) ----
__global__ __launch_bounds__(1024) void k_perm() {
    __shared__ int hist[64];
    int t = threadIdx.x;
    if (t < 64) hist[t] = 0;
    __syncthreads();
    for (int n = t; n < NN; n += 1024)
        atomicAdd(&hist[min(g_cnt[n], 63)], 1);
    __syncthreads();
    if (t < 64) {
        int v = hist[t];
        int incl = v;
#pragma unroll
        for (int off = 1; off < 64; off <<= 1) {
            int u = __shfl_up(incl, off, 64);
            if (t >= off) incl += u;
        }
        hist[t] = incl - v;                      // exclusive base -> cursor
    }
    __syncthreads();
    for (int n = t; n < NN; n += 1024) {
        int s = atomicAdd(&hist[min(g_cnt[n], 63)], 1);
        int blk, grp;
        if (s < 12288) {                         // 48 full-wave groups per block
            int c = s >> 2, r = s & 3;
            blk = c & 255;
            grp = ((c >> 8) << 2) + r;           // grp 0..47 (12 full waves)
        } else {                                 // top 512 nodes -> half-wave grps
            int l = s - 12288;
            blk = l & 255;
            grp = 48 + (l >> 8);                 // grp 48..49
        }
        g_perm[blk * NPB + grp] = n;
    }
}

// ---- one round. 256 blocks x 800 thr = 50 nodes x 16 lanes; 1 block/CU. ----
// v8 = v5 + amdgpu_waves_per_eu(4,4): grid is exactly 1 block/CU, so the
// allocator's default 2-blocks/CU target (VGPR<=64, r2 evidence: 60MB/dispatch
// scratch spills) buys nothing. Pin 4 waves/EU -> VGPR budget 128 (the max
// launchable for a 13-wave workgroup); resident waves unchanged at 13/CU.
__global__ __launch_bounds__(RTHR)
__attribute__((amdgpu_waves_per_eu(4, 4)))
void k_round(float* __restrict__ out_final, int flip, int last) {
    __shared__ __align__(16) float s_pack[PACKN];
    int t = threadIdx.x;
    {   // straight coalesced float4 copy of the pre-transposed pack
        const float4* srcp = (const float4*)g_wpack;
        float4* dstp = (float4*)s_pack;
        for (int idx = t; idx < PACKN / 4; idx += RTHR) dstp[idx] = srcp[idx];
    }
    __syncthreads();

    const float* s_W2  = s_pack + OFF_W2;
    const float* s_crT = s_pack + OFF_CR;
    const float* s_wi  = s_pack + OFF_WI;
    const float* s_wh  = s_pack + OFF_WH;
    const float* s_cb  = s_pack + OFF_CB;
    const float* s_bi  = s_pack + OFF_BI;
    const float* s_bh  = s_pack + OFF_BH;

    const float* cur = flip ? g_outB : g_outA;
    float*       nxt = flip ? g_outA : g_outB;

    const int grp = t >> 4, j = t & 15;          // lane j inside group (grp < 50)
    const int n = min(max(g_perm[blockIdx.x * NPB + grp], 0), NN - 1);
    int deg = min(g_cnt[n], BCAP);               // clamp guards replay corruption
    if (last && j == 0) g_cnt[n] = 0;            // reset for next call's k_setup
    const int base = n * BCAP;

    // ---- src prefetch: lane j holds slots j, 16+j, 32+j, 48+j (64B/load) ----
    int s0 = min(max(g_srcB[base + j], 0), NN - 1);
    int s1 = min(max(g_srcB[base + 16 + j], 0), NN - 1);
    int s2 = min(max(g_srcB[base + 32 + j], 0), NN - 1);
    int s3 = min(max(g_srcB[base + 48 + j], 0), NN - 1);

    // ---- G-row accumulation (registers, zero LDS) ----
    float Gd[16];
#pragma unroll
    for (int d = 0; d < 16; ++d) Gd[d] = 0.0f;
    float r16 = 0.0f;

#pragma unroll
    for (int seg = 0; seg < 4; ++seg) {
        int segq = seg << 4;
        if (segq >= deg) break;
        int cnt = min(deg - segq, 16);
        int sv = (seg == 0) ? s0 : (seg == 1) ? s1 : (seg == 2) ? s2 : s3;
        const float* ehp = g_ehsB + (base + segq) * 16 + j;
#pragma unroll 4
        for (int qq = 0; qq < cnt; ++qq) {
            int s = __shfl(sv, qq, 16);          // register broadcast, no load
            const float* orow = cur + s * 16;
            float ej = ehp[qq << 4];             // coalesced 64B per group
            float4 o0 = *(const float4*)(orow + 0);  // broadcast
            float4 o1 = *(const float4*)(orow + 4);
            float4 o2 = *(const float4*)(orow + 8);
            float4 o3 = *(const float4*)(orow + 12);
            Gd[0]  += ej * o0.x; Gd[1]  += ej * o0.y; Gd[2]  += ej * o0.z; Gd[3]  += ej * o0.w;
            Gd[4]  += ej * o1.x; Gd[5]  += ej * o1.y; Gd[6]  += ej * o1.z; Gd[7]  += ej * o1.w;
            Gd[8]  += ej * o2.x; Gd[9]  += ej * o2.y; Gd[10] += ej * o2.z; Gd[11] += ej * o2.w;
            Gd[12] += ej * o3.x; Gd[13] += ej * o3.y; Gd[14] += ej * o3.z; Gd[15] += ej * o3.w;
            r16 += orow[j];
        }
    }

    // ---- contraction: part[k'] via b128 s_W2 reads ----
    const float* wj = s_W2 + j * 276;
    float part[16];
#pragma unroll
    for (int kp = 0; kp < 16; ++kp) {
        const float* w = wj + kp * 16;
        float4 w0 = *(const float4*)(w + 0);
        float4 w1 = *(const float4*)(w + 4);
        float4 w2 = *(const float4*)(w + 8);
        float4 w3 = *(const float4*)(w + 12);
        part[kp] = Gd[0] * w0.x + Gd[1] * w0.y + Gd[2] * w0.z + Gd[3] * w0.w
                 + Gd[4] * w1.x + Gd[5] * w1.y + Gd[6] * w1.z + Gd[7] * w1.w
                 + Gd[8] * w2.x + Gd[9] * w2.y + Gd[10] * w2.z + Gd[11] * w2.w
                 + Gd[12] * w3.x + Gd[13] * w3.y + Gd[14] * w3.z + Gd[15] * w3.w;
    }
    {   // fold bias row: part[k'] += r16 * b2[j*16+k']
        float4 b0 = *(const float4*)(wj + 256);
        float4 b1 = *(const float4*)(wj + 260);
        float4 b2v = *(const float4*)(wj + 264);
        float4 b3 = *(const float4*)(wj + 268);
        part[0] += r16 * b0.x;  part[1] += r16 * b0.y;  part[2] += r16 * b0.z;  part[3] += r16 * b0.w;
        part[4] += r16 * b1.x;  part[5] += r16 * b1.y;  part[6] += r16 * b1.z;  part[7] += r16 * b1.w;
        part[8] += r16 * b2v.x; part[9] += r16 * b2v.y; part[10] += r16 * b2v.z; part[11] += r16 * b2v.w;
        part[12] += r16 * b3.x; part[13] += r16 * b3.y; part[14] += r16 * b3.z; part[15] += r16 * b3.w;
    }

    // ---- j-reduction: halving butterfly, 15 shfl_xor ----
    // rule #20: private-array indices compile-time; runtime choice via VALUE
    // selects (v_cndmask), never via index.
    const bool sel0 = (j & 1) != 0;
    const bool sel1 = ((j >> 1) & 1) != 0;
    const bool sel2 = ((j >> 2) & 1) != 0;
    const bool sel3 = ((j >> 3) & 1) != 0;

    float w8[8];
#pragma unroll
    for (int i = 0; i < 8; ++i) {
        float a = part[2 * i], b = part[2 * i + 1];
        float keepv = sel0 ? b : a;
        float othv  = sel0 ? a : b;
        w8[i] = keepv + __shfl_xor(othv, 1);
    }
    float w4[4];
#pragma unroll
    for (int i = 0; i < 4; ++i) {
        float a = w8[2 * i], b = w8[2 * i + 1];
        float keepv = sel1 ? b : a;
        float othv  = sel1 ? a : b;
        w4[i] = keepv + __shfl_xor(othv, 2);
    }
    float w2[2];
#pragma unroll
    for (int i = 0; i < 2; ++i) {
        float a = w4[2 * i], b = w4[2 * i + 1];
        float keepv = sel2 ? b : a;
        float othv  = sel2 ? a : b;
        w2[i] = keepv + __shfl_xor(othv, 4);
    }
    float aggr;
    {
        float a = w2[0], b = w2[1];
        float keepv = sel3 ? b : a;
        float othv  = sel3 ? a : b;
        aggr = keepv + __shfl_xor(othv, 8);
    }
    float invd = 1.0f / (float)(deg > 0 ? deg : 1);
    float a_k = aggr * invd;
    const int k = j;

    // ---- node update: conv + GRU (b128 LDS weights) ----
    const float* nrow = cur + n * 16;
    float4 q0 = *(const float4*)(nrow + 0);
    float4 q1 = *(const float4*)(nrow + 4);
    float4 q2 = *(const float4*)(nrow + 8);
    float4 q3 = *(const float4*)(nrow + 12);
    float o[16] = {q0.x, q0.y, q0.z, q0.w, q1.x, q1.y, q1.z, q1.w,
                   q2.x, q2.y, q2.z, q2.w, q3.x, q3.y, q3.z, q3.w};
    float ok = nrow[j];                          // own element: direct coalesced load

    float mcc = s_cb[k] + a_k;
    {
        const float* c = s_crT + k * 20;
        float4 c0 = *(const float4*)(c + 0);
        float4 c1 = *(const float4*)(c + 4);
        float4 c2 = *(const float4*)(c + 8);
        float4 c3 = *(const float4*)(c + 12);
        mcc += o[0] * c0.x + o[1] * c0.y + o[2] * c0.z + o[3] * c0.w
             + o[4] * c1.x + o[5] * c1.y + o[6] * c1.z + o[7] * c1.w
             + o[8] * c2.x + o[9] * c2.y + o[10] * c2.z + o[11] * c2.w
             + o[12] * c3.x + o[13] * c3.y + o[14] * c3.z + o[15] * c3.w;
    }
    float m = fmaxf(mcc, 0.0f);

    float md[16];
#pragma unroll
    for (int d = 0; d < 16; ++d) md[d] = __shfl(m, d, 16);

    float ir = s_bi[k], iz = s_bi[16 + k], in_ = s_bi[32 + k];
    float hr = s_bh[k], hz = s_bh[16 + k], hh = s_bh[32 + k];
#pragma unroll
    for (int g = 0; g < 3; ++g) {
        const float* wrow_i = s_wi + (g * 16 + k) * 20;
        const float* wrow_h = s_wh + (g * 16 + k) * 20;
        float acc_i = 0.0f, acc_h = 0.0f;
#pragma unroll
        for (int d4 = 0; d4 < 4; ++d4) {
            float4 wiv = *(const float4*)(wrow_i + d4 * 4);
            float4 whv = *(const float4*)(wrow_h + d4 * 4);
            acc_i += md[d4 * 4] * wiv.x + md[d4 * 4 + 1] * wiv.y
                   + md[d4 * 4 + 2] * wiv.z + md[d4 * 4 + 3] * wiv.w;
            acc_h += o[d4 * 4] * whv.x + o[d4 * 4 + 1] * whv.y
                   + o[d4 * 4 + 2] * whv.z + o[d4 * 4 + 3] * whv.w;
        }
        if (g == 0) { ir += acc_i; hr += acc_h; }
        else if (g == 1) { iz += acc_i; hz += acc_h; }
        else { in_ += acc_i; hh += acc_h; }
    }
    float rg = 1.0f / (1.0f + __expf(-(ir + hr)));
    float z  = 1.0f / (1.0f + __expf(-(iz + hz)));
    float nh = tanhf(in_ + rg * hh);
    float hnew = (1.0f - z) * nh + z * ok;

    if (last) out_final[n * 16 + k] = hnew;
    else      nxt[n * 16 + k] = hnew;
}

extern "C" void kernel_launch(void* const* d_in, const int* in_sizes, int n_in,
                              void* d_out, int out_size, void* d_ws, size_t ws_size,
                              hipStream_t stream) {
    const float* x         = (const float*)d_in[0];
    const int*   ei        = (const int*)d_in[1];
    const float* edge_attr = (const float*)d_in[2];
    const float* lin0_w    = (const float*)d_in[3];
    const float* lin0_b    = (const float*)d_in[4];
    const float* nn1_w     = (const float*)d_in[5];
    const float* nn1_b     = (const float*)d_in[6];
    const float* nn2_w     = (const float*)d_in[7];
    const float* nn2_b     = (const float*)d_in[8];
    const float* conv_root = (const float*)d_in[9];
    const float* conv_bias = (const float*)d_in[10];
    const float* gru_w_ih  = (const float*)d_in[11];
    const float* gru_w_hh  = (const float*)d_in[12];
    const float* gru_b_ih  = (const float*)d_in[13];
    const float* gru_b_hh  = (const float*)d_in[14];
    float* out = (float*)d_out;

    k_setup<<<NE / 256, 256, 0, stream>>>(ei, x, lin0_w, lin0_b, edge_attr,
                                          nn1_w, nn1_b, nn2_w, nn2_b, conv_root,
                                          conv_bias, gru_w_ih, gru_w_hh,
                                          gru_b_ih, gru_b_hh);
    k_perm<<<1, 1024, 0, stream>>>();

    for (int r = 0; r < 6; ++r) {
        k_round<<<NN / NPB, RTHR, 0, stream>>>(out, r & 1, r == 5 ? 1 : 0);
    }
}